// Round 2
// baseline (339.849 us; speedup 1.0000x reference)
//
#include <hip/hip_runtime.h>
#include <math.h>

#define NV    49
#define Himg  256
#define Wimg  256
#define RW    240
#define RWH   (RW*RW)          // 57600
#define NPIX  (4*RWH)          // 230400
#define ROWF  (Wimg*3)         // 768 floats per image row
#define IMGF  (Himg*Wimg*3)    // 196608 floats per view image
#define NBLK  (NPIX/64)        // 3600 blocks

// 4B-aligned wide vector loads: gfx950 global loads are legal at dword
// alignment; LLVM emits global_load_dwordx4/x2 for these types.
typedef float f4u __attribute__((ext_vector_type(4), aligned(4)));
typedef float f2u __attribute__((ext_vector_type(2), aligned(4)));

// ---------------------------------------------------------------------------
// Fused kernel: warp-all + color loss + angular gauss + stable-rank tail sum
// + edge-aware smoothness.
// 64 pixels/block, 7 sub-waves per pixel group: wave `sub` owns angular row
// u == sub (7 views). Stage 1 issues ALL 28 row-loads (dwordx4+dwordx2)
// before any interpolation math -> deep per-wave MLP.
// __launch_bounds__(448,4): allow ~128 VGPRs so the loads stay in flight.
// ---------------------------------------------------------------------------

__global__ __launch_bounds__(448, 4) void color_kernel(
    const float* __restrict__ pred, const float* __restrict__ x,
    const float* __restrict__ y, const int* __restrict__ epoch_p,
    double* __restrict__ acc)
{
    __shared__ float s_cl[64 * NV];
    __shared__ float s_g [64 * NV];
    __shared__ float sred[8];

    const int tid = threadIdx.x;
    const int pix = tid & 63;
    // wave-uniform angular row index (SGPR): view-base address math is scalar
    const int sub = __builtin_amdgcn_readfirstlane(tid >> 6);   // 0..6

    // XCD band swizzle: XCD k (= bid%8) gets a contiguous 450-block band
    int lb  = (blockIdx.x & 7) * (NBLK/8) + (blockIdx.x >> 3);
    int pid = lb * 64 + pix;
    int b   = pid / RWH;
    int rem = pid - b * RWH;
    int ry  = rem / RW;
    int yy  = 8 + ry;
    int xx  = 8 + (rem - ry * RW);

    int pidx = (b * Himg + yy) * Wimg + xx;
    float p = pred[pidx];
    const int epoch = *epoch_p;          // scalar load, hoisted early

    const float* xv    = x + (size_t)b * (49 * IMGF);
    const float* cbase = xv + (24 * IMGF) + (yy * Wimg + xx) * 3;
    // center texel via one wide load (cbase+3 is always in-bounds: view 24)
    f4u cv = *(const f4u*)cbase;
    float c0 = cv.x, c1 = cv.y, c2 = cv.z;

    float* mycl = s_cl + pix * NV;
    float* myg  = s_g  + pix * NV;

    // separable x-interpolants (7), registers after full unroll
    int co[7]; float txv[7];
    #pragma unroll
    for (int vv = 0; vv < 7; vv++) {
        float cx = fminf(fmaxf((float)xx + p * (float)(vv-3), 0.0f), 255.0f);
        float x0f = floorf(cx);
        float tx = cx - x0f;
        int ix0 = (int)x0f;
        if (ix0 >= 255) { ix0 = 254; tx = 1.0f; }  // same bilinear result
        co[vv] = ix0 * 3; txv[vv] = tx;
    }

    // ---- stage 1: this wave's u-row (7 views); cl kept in regs AND in LDS
    float creg[7];
    {
        float cy = fminf(fmaxf((float)yy + p * (float)(sub-3), 0.0f), 255.0f);
        float y0f = floorf(cy);
        float ty = cy - y0f;
        int iy0 = (int)y0f;
        int iy1 = min(iy0+1, 255);
        int ro0 = iy0*ROWF, ro1 = iy1*ROWF;
        const float* vbase = xv + sub * 7 * IMGF;   // SGPR base

        // pass A: issue all 28 loads (7 views x 2 rows x (x4 + x2))
        f4u a0[7], b0[7]; f2u a1[7], b1[7];
        #pragma unroll
        for (int vv = 0; vv < 7; vv++) {
            const float* s0p = vbase + vv*IMGF + ro0 + co[vv];
            const float* s1p = vbase + vv*IMGF + ro1 + co[vv];
            a0[vv] = *(const f4u*)s0p;
            a1[vv] = *(const f2u*)(s0p + 4);
            b0[vv] = *(const f4u*)s1p;
            b1[vv] = *(const f2u*)(s1p + 4);
        }

        // pass B: bilinear interp + color loss (identical arithmetic/order)
        #pragma unroll
        for (int vv = 0; vv < 7; vv++) {
            float tx = txv[vv];
            float s00 = a0[vv].x, s01 = a0[vv].y, s02 = a0[vv].z;
            float s03 = a0[vv].w, s04 = a1[vv].x, s05 = a1[vv].y;
            float s10 = b0[vv].x, s11 = b0[vv].y, s12 = b0[vv].z;
            float s13 = b0[vv].w, s14 = b1[vv].x, s15 = b1[vv].y;
            float h0 = s00 + tx*(s03-s00);
            float h1 = s01 + tx*(s04-s01);
            float h2 = s02 + tx*(s05-s02);
            float k0 = s10 + tx*(s13-s10);
            float k1 = s11 + tx*(s14-s11);
            float k2 = s12 + tx*(s15-s12);
            float o0 = h0 + ty*(k0-h0);
            float o1 = h1 + ty*(k1-h1);
            float o2 = h2 + ty*(k2-h2);
            float cl = (fabsf(o0-c0)+fabsf(o1-c1)+fabsf(o2-c2)) * (1.0f/3.0f);
            creg[vv] = cl;
            mycl[sub*7 + vv] = cl;
        }
    }

    // grad loss on the center-row wave (it already touches the center view)
    if (sub == 3) {
        float lx = 0.0f, ly = 0.0f;
        if (xx <= 246) {
            f4u q0 = *(const f4u*)cbase;
            f2u q1 = *(const f2u*)(cbase + 4);
            float wx = __expf(-50.0f * (fabsf(q0.w-c0) + fabsf(q1.x-c1) + fabsf(q1.y-c2)));
            lx = wx * fabsf(pred[pidx + 1] - p);
        }
        if (yy <= 246) {
            f4u r = *(const f4u*)(cbase + ROWF);
            float wy = __expf(-50.0f * (fabsf(r.x-c0) + fabsf(r.y-c1) + fabsf(r.z-c2)));
            ly = wy * fabsf(pred[pidx + Wimg] - p);
        }
        #pragma unroll
        for (int off = 32; off > 0; off >>= 1) {
            lx += __shfl_down(lx, off);
            ly += __shfl_down(ly, off);
        }
        if (pix == 0) {
            atomicAdd(acc + 1, (double)lx);
            atomicAdd(acc + 2, (double)ly);
        }
    }
    __syncthreads();

    // ---- stage 2: angular gaussian, one u-row per wave (edge-replicated) ----
    if (epoch > 0) {
        const int um1 = (sub > 0) ? sub-1 : 0;
        const int up1 = (sub < 6) ? sub+1 : 6;
        const float* rm = mycl + um1*7;
        const float* rc = mycl + sub*7;
        const float* rp = mycl + up1*7;
        #pragma unroll
        for (int vv = 0; vv < 7; vv++) {
            const int vm = (vv > 0) ? vv-1 : 0;
            const int vp = (vv < 6) ? vv+1 : 6;
            // exact tap order as reference (row-major, left-associated)
            myg[sub*7 + vv] =
                0.0751f*rm[vm] + 0.1238f*rm[vv] + 0.0751f*rm[vp] +
                0.1238f*rc[vm] + 0.2042f*rc[vv] + 0.1238f*rc[vp] +
                0.0751f*rp[vm] + 0.1238f*rp[vv] + 0.0751f*rp[vp];
        }
    }
    __syncthreads();

    // ---- stage 3: stable-descending rank via packed u64 keys ----
    // this wave ranks exactly the 7 views it computed; cl values from regs
    const float* key = (epoch > 0) ? myg : mycl;
    float yval = y[pidx];

    unsigned long long kn[7];
    int cnt[7];
    #pragma unroll
    for (int i = 0; i < 7; i++) {
        int n = sub*7 + i;
        unsigned int bb = __float_as_uint(key[n]);   // key >= 0 -> bits ordered
        kn[i] = (((unsigned long long)bb) << 8) | (unsigned long long)(255 - n);
        cnt[i] = 0;
    }
    #pragma unroll 7
    for (int m = 0; m < NV; m++) {
        unsigned int bm = __float_as_uint(key[m]);
        unsigned long long km = (((unsigned long long)bm) << 8) | (unsigned long long)(255 - m);
        #pragma unroll
        for (int i = 0; i < 7; i++)
            cnt[i] += (km > kn[i]) ? 1 : 0;
    }
    float tail = 0.0f;
    #pragma unroll
    for (int i = 0; i < 7; i++)
        tail += ((float)cnt[i] > yval) ? creg[i] : 0.0f;
    float contrib = tail * (49.0f / (49.0f - yval));

    #pragma unroll
    for (int off = 32; off > 0; off >>= 1)
        contrib += __shfl_down(contrib, off);
    if (pix == 0) sred[sub] = contrib;
    __syncthreads();
    if (tid == 0) {
        double s = 0.0;
        #pragma unroll
        for (int i = 0; i < 7; i++) s += (double)sred[i];
        atomicAdd(acc + 0, s);
    }
}

__global__ void finalize_kernel(const double* __restrict__ acc,
                                float* __restrict__ out)
{
    double cl = acc[0] / 11289600.0;           // 4*49*240*240
    double gl = (acc[1] + acc[2]) / (2.0 * 229440.0);  // 4*240*239 each
    out[0] = (float)(cl + 0.1 * gl);
}

extern "C" void kernel_launch(void* const* d_in, const int* in_sizes, int n_in,
                              void* d_out, int out_size, void* d_ws, size_t ws_size,
                              hipStream_t stream)
{
    const float* pred  = (const float*)d_in[0];
    const float* x     = (const float*)d_in[1];
    const float* y     = (const float*)d_in[2];
    const int*   epoch = (const int*)d_in[3];
    double* acc = (double*)d_ws;

    hipMemsetAsync(acc, 0, 3 * sizeof(double), stream);
    color_kernel<<<NBLK, 448, 0, stream>>>(pred, x, y, epoch, acc);
    finalize_kernel<<<1, 1, 0, stream>>>(acc, (float*)d_out);
}

// Round 3
// 320.305 us; speedup vs baseline: 1.0610x; 1.0610x over previous
//
#include <hip/hip_runtime.h>
#include <math.h>

#define NV    49
#define NVP   52               // padded per-pixel key stride: 52*4B = 208B = 16B-aligned rows
#define Himg  256
#define Wimg  256
#define RW    240
#define RWH   (RW*RW)          // 57600
#define NPIX  (4*RWH)          // 230400
#define ROWF  (Wimg*3)         // 768 floats per image row
#define IMGF  (Himg*Wimg*3)    // 196608 floats per view image
#define NBLK  (NPIX/64)        // 3600 blocks

// 4B-aligned wide vector loads (gfx950 global loads legal at dword align)
typedef float f4u __attribute__((ext_vector_type(4), aligned(4)));
typedef float f2u __attribute__((ext_vector_type(2), aligned(4)));
typedef float f4a __attribute__((ext_vector_type(4), aligned(16)));

// ---------------------------------------------------------------------------
// Fused kernel. 64 pixels/block, 7 waves: wave `sub` owns angular row u==sub.
// Stage 1 is an explicit 3-ahead software pipeline: loads of view vv+3 are
// pinned ABOVE compute of view vv with sched_barrier(0) fences, so ~12 wide
// loads stay in flight per wave (the compiler otherwise sinks loads to uses,
// leaving depth ~1-2 -> latency-serial; R2 measured exactly that).
// Stage 3 reads all 49 rank keys via 13x ds_read_b128 into registers, then
// runs the fully-unrolled 49x7 u64 compare loop on registers only.
// ---------------------------------------------------------------------------

__global__ __launch_bounds__(448, 4) void color_kernel(
    const float* __restrict__ pred, const float* __restrict__ x,
    const float* __restrict__ y, const int* __restrict__ epoch_p,
    double* __restrict__ acc)
{
    __shared__ float s_cl[64 * NVP];
    __shared__ float s_g [64 * NVP];
    __shared__ float sred[8];

    const int tid = threadIdx.x;
    const int pix = tid & 63;
    // wave-uniform angular row index (SGPR)
    const int sub = __builtin_amdgcn_readfirstlane(tid >> 6);   // 0..6

    // XCD band swizzle
    int lb  = (blockIdx.x & 7) * (NBLK/8) + (blockIdx.x >> 3);
    int pid = lb * 64 + pix;
    int b   = pid / RWH;
    int rem = pid - b * RWH;
    int ry  = rem / RW;
    int yy  = 8 + ry;
    int xx  = 8 + (rem - ry * RW);

    int pidx = (b * Himg + yy) * Wimg + xx;
    float p    = pred[pidx];
    float yval = y[pidx];                // hoisted: latency hides under stage 1
    const int epoch = *epoch_p;

    const float* xv    = x + (size_t)b * (49 * IMGF);
    const float* cbase = xv + (24 * IMGF) + (yy * Wimg + xx) * 3;
    f4u cv = *(const f4u*)cbase;         // center texel (cbase+3 in-bounds)
    float c0 = cv.x, c1 = cv.y, c2 = cv.z;

    float* mycl = s_cl + pix * NVP;
    float* myg  = s_g  + pix * NVP;

    // separable x-interpolants (7), registers after full unroll
    int co[7]; float txv[7];
    #pragma unroll
    for (int vv = 0; vv < 7; vv++) {
        float cx = fminf(fmaxf((float)xx + p * (float)(vv-3), 0.0f), 255.0f);
        float x0f = floorf(cx);
        float tx = cx - x0f;
        int ix0 = (int)x0f;
        if (ix0 >= 255) { ix0 = 254; tx = 1.0f; }  // same bilinear result
        co[vv] = ix0 * 3; txv[vv] = tx;
    }

    // ---- stage 1: this wave's u-row (7 views), 3-ahead pipelined ----
    float creg[7];
    {
        float cy = fminf(fmaxf((float)yy + p * (float)(sub-3), 0.0f), 255.0f);
        float y0f = floorf(cy);
        float ty = cy - y0f;
        int iy0 = (int)y0f;
        int iy1 = min(iy0+1, 255);
        int ro0 = iy0*ROWF, ro1 = iy1*ROWF;
        const float* vbase = xv + sub * 7 * IMGF;   // SGPR base

        f4u a0[4], b0[4]; f2u a1[4], b1[4];

#define LOADV(VV, S) { \
        const float* s0p = vbase + (VV)*IMGF + ro0 + co[VV]; \
        const float* s1p = vbase + (VV)*IMGF + ro1 + co[VV]; \
        a0[S] = *(const f4u*)s0p;  a1[S] = *(const f2u*)(s0p + 4); \
        b0[S] = *(const f4u*)s1p;  b1[S] = *(const f2u*)(s1p + 4); }

        LOADV(0,0) LOADV(1,1) LOADV(2,2)
        __builtin_amdgcn_sched_barrier(0);

        #pragma unroll
        for (int vv = 0; vv < 7; vv++) {
            if (vv + 3 < 7) { LOADV(vv+3, (vv+3)&3) }
            __builtin_amdgcn_sched_barrier(0);
            const int S = vv & 3;                 // compile-time (full unroll)
            float tx = txv[vv];
            float s00 = a0[S].x, s01 = a0[S].y, s02 = a0[S].z;
            float s03 = a0[S].w, s04 = a1[S].x, s05 = a1[S].y;
            float s10 = b0[S].x, s11 = b0[S].y, s12 = b0[S].z;
            float s13 = b0[S].w, s14 = b1[S].x, s15 = b1[S].y;
            float h0 = s00 + tx*(s03-s00);
            float h1 = s01 + tx*(s04-s01);
            float h2 = s02 + tx*(s05-s02);
            float k0 = s10 + tx*(s13-s10);
            float k1 = s11 + tx*(s14-s11);
            float k2 = s12 + tx*(s15-s12);
            float o0 = h0 + ty*(k0-h0);
            float o1 = h1 + ty*(k1-h1);
            float o2 = h2 + ty*(k2-h2);
            float cl = (fabsf(o0-c0)+fabsf(o1-c1)+fabsf(o2-c2)) * (1.0f/3.0f);
            creg[vv] = cl;
            mycl[sub*7 + vv] = cl;
            __builtin_amdgcn_sched_barrier(0);
        }
#undef LOADV
    }

    // grad loss on the center-row wave
    if (sub == 3) {
        float lx = 0.0f, ly = 0.0f;
        if (xx <= 246) {
            f4u q0 = *(const f4u*)cbase;
            f2u q1 = *(const f2u*)(cbase + 4);
            float wx = __expf(-50.0f * (fabsf(q0.w-c0) + fabsf(q1.x-c1) + fabsf(q1.y-c2)));
            lx = wx * fabsf(pred[pidx + 1] - p);
        }
        if (yy <= 246) {
            f4u r = *(const f4u*)(cbase + ROWF);
            float wy = __expf(-50.0f * (fabsf(r.x-c0) + fabsf(r.y-c1) + fabsf(r.z-c2)));
            ly = wy * fabsf(pred[pidx + Wimg] - p);
        }
        #pragma unroll
        for (int off = 32; off > 0; off >>= 1) {
            lx += __shfl_down(lx, off);
            ly += __shfl_down(ly, off);
        }
        if (pix == 0) {
            atomicAdd(acc + 1, (double)lx);
            atomicAdd(acc + 2, (double)ly);
        }
    }
    __syncthreads();

    // ---- stage 2: angular gaussian, one u-row per wave (edge-replicated) ----
    if (epoch > 0) {
        const int um1 = (sub > 0) ? sub-1 : 0;
        const int up1 = (sub < 6) ? sub+1 : 6;
        const float* rm = mycl + um1*7;
        const float* rc = mycl + sub*7;
        const float* rp = mycl + up1*7;
        #pragma unroll
        for (int vv = 0; vv < 7; vv++) {
            const int vm = (vv > 0) ? vv-1 : 0;
            const int vp = (vv < 6) ? vv+1 : 6;
            // exact tap order as reference (row-major, left-associated)
            myg[sub*7 + vv] =
                0.0751f*rm[vm] + 0.1238f*rm[vv] + 0.0751f*rm[vp] +
                0.1238f*rc[vm] + 0.2042f*rc[vv] + 0.1238f*rc[vp] +
                0.0751f*rp[vm] + 0.1238f*rp[vv] + 0.0751f*rp[vp];
        }
    }
    __syncthreads();

    // ---- stage 3: stable-descending rank via packed u64 keys ----
    const float* keyb = (epoch > 0) ? myg : mycl;

    // all 49 keys -> registers via 13x ds_read_b128 (rows are 16B-aligned)
    f4a kv[13];
    #pragma unroll
    for (int i = 0; i < 13; i++)
        kv[i] = *(const f4a*)(keyb + 4*i);

    // own-view reference keys (runtime sub -> read from LDS, not kv)
    unsigned long long kn[7];
    int cnt[7];
    #pragma unroll
    for (int i = 0; i < 7; i++) {
        int n = sub*7 + i;
        unsigned int bb = __float_as_uint(keyb[n]);  // key >= 0 -> bits ordered
        kn[i] = (((unsigned long long)bb) << 8) | (unsigned long long)(255 - n);
        cnt[i] = 0;
    }
    #pragma unroll
    for (int m = 0; m < NV; m++) {
        unsigned int bm = __float_as_uint(kv[m>>2][m&3]);   // static idx
        unsigned long long km = (((unsigned long long)bm) << 8) | (unsigned long long)(255 - m);
        #pragma unroll
        for (int i = 0; i < 7; i++)
            cnt[i] += (km > kn[i]) ? 1 : 0;
    }
    float tail = 0.0f;
    #pragma unroll
    for (int i = 0; i < 7; i++)
        tail += ((float)cnt[i] > yval) ? creg[i] : 0.0f;
    float contrib = tail * (49.0f / (49.0f - yval));

    #pragma unroll
    for (int off = 32; off > 0; off >>= 1)
        contrib += __shfl_down(contrib, off);
    if (pix == 0) sred[sub] = contrib;
    __syncthreads();
    if (tid == 0) {
        double s = 0.0;
        #pragma unroll
        for (int i = 0; i < 7; i++) s += (double)sred[i];
        atomicAdd(acc + 0, s);
    }
}

__global__ void finalize_kernel(const double* __restrict__ acc,
                                float* __restrict__ out)
{
    double cl = acc[0] / 11289600.0;           // 4*49*240*240
    double gl = (acc[1] + acc[2]) / (2.0 * 229440.0);  // 4*240*239 each
    out[0] = (float)(cl + 0.1 * gl);
}

extern "C" void kernel_launch(void* const* d_in, const int* in_sizes, int n_in,
                              void* d_out, int out_size, void* d_ws, size_t ws_size,
                              hipStream_t stream)
{
    const float* pred  = (const float*)d_in[0];
    const float* x     = (const float*)d_in[1];
    const float* y     = (const float*)d_in[2];
    const int*   epoch = (const int*)d_in[3];
    double* acc = (double*)d_ws;

    hipMemsetAsync(acc, 0, 3 * sizeof(double), stream);
    color_kernel<<<NBLK, 448, 0, stream>>>(pred, x, y, epoch, acc);
    finalize_kernel<<<1, 1, 0, stream>>>(acc, (float*)d_out);
}